// Round 16
// baseline (24.915 us; speedup 1.0000x reference)
//
#include <hip/hip_runtime.h>

typedef __attribute__((ext_vector_type(8))) short short8;
typedef __attribute__((ext_vector_type(4))) short short4v;
typedef __attribute__((ext_vector_type(4))) float float4v;

static __device__ __forceinline__ short f2bf(float x) {
    unsigned u = __float_as_uint(x);
    unsigned r = (u + 0x7FFFu + ((u >> 16) & 1u)) >> 16;   // RNE
    return (short)r;
}
static __device__ __forceinline__ float bf2f(short h) {
    return __uint_as_float(((unsigned)(unsigned short)h) << 16);
}
struct BfPair { short hi, lo; };
static __device__ __forceinline__ BfPair split2(float x) {   // W staging only
    BfPair r;
    r.hi = f2bf(x);
    r.lo = f2bf(x - bf2f(r.hi));
    return r;
}

static __device__ __forceinline__ unsigned cvt_pk_bf16(float a, float b) {
    unsigned r;
    asm("v_cvt_pk_bf16_f32 %0, %1, %2" : "=v"(r) : "v"(a), "v"(b));
    return r;   // low16 = bf16(a), high16 = bf16(b)
}

// R4-R7-proven split: hi = truncation (bit ops, residual exact), lo = RNE of
// residual via cvt_pk. (cvt_pk-based HI plane fails correctness — R9/R10.)
static __device__ __forceinline__ void split8(const float x[8], short8& hi, short8& lo) {
    union U { short8 s; unsigned u[4]; } H, L;
    #pragma unroll
    for (int q = 0; q < 4; ++q) {
        unsigned ue = __float_as_uint(x[2*q]);
        unsigned uo = __float_as_uint(x[2*q+1]);
        H.u[q] = (ue >> 16) | (uo & 0xFFFF0000u);
        float re = x[2*q]   - __uint_as_float(ue & 0xFFFF0000u);
        float ro = x[2*q+1] - __uint_as_float(uo & 0xFFFF0000u);
        L.u[q] = cvt_pk_bf16(re, ro);
    }
    hi = H.s; lo = L.s;
}

static __device__ __forceinline__ float max3f(float a, float b, float c) {
    float d;
    asm("v_max3_f32 %0, %1, %2, %3" : "=v"(d) : "v"(a), "v"(b), "v"(c));
    return d;
}

#define MF(c, a, b) c = __builtin_amdgcn_mfma_f32_16x16x32_bf16(a, b, c, 0, 0, 0)

// Block = 1024 threads (16 waves), one sample per thread, (1024,2) -> 128-reg
// cap, 4 waves/SIMD (max occupancy this footprint permits).
// R16: tail prefetch moved AFTER VI. Ledger: VI live = crd[64]+p[16]+v[16]+
// nv[16] = 112 (+step temps) -- holding 12 tail floats across the 19 unrolled
// steps pushed the loop over the 128 cap into per-step parking (R12/R15's
// occupancy changes were null because of this). 16 waves/CU of TLP hide the
// tail loads without prefetch.
__global__ __launch_bounds__(1024, 2) void vpn_kernel(
    const float* __restrict__ obs,
    const float* __restrict__ W_phi,
    const float* __restrict__ b_phi,
    const float* __restrict__ W_logit,
    const float* __restrict__ b_logit,
    float* __restrict__ out, int B)
{
    __shared__ __align__(16) unsigned short Wfh[6 * 64 * 8];   //  6144 B
    __shared__ __align__(16) unsigned short Wfl[6 * 64 * 8];   //  6144 B
    __shared__ __align__(16) float buf[16][840];               // 53760 B

    const int t    = threadIdx.x;
    const int lane = t & 63;
    const int wave = t >> 6;
    const int smp  = blockIdx.x * 1024 + t;
    const int wavebase = blockIdx.x * 1024 + wave * 64;

    // ---------------- stage W fragments (once per block) ----------------
    if (t < 768) {
        int H = t;                            // 0..767 half-fragments
        int f = H >> 7, rem = H & 127;
        int L = rem >> 1, q = rem & 1;
        int jt = f >> 1, kc = f & 1;
        int j = jt * 16 + (L & 15), h = L >> 4;
        int k = kc * 32 + h * 8 + q * 4;
        float4 w = make_float4(0.f, 0.f, 0.f, 0.f);
        if (k < 48) w = *(const float4*)(W_phi + j * 48 + k);
        short4v hv, lv;
        BfPair s0 = split2(w.x), s1 = split2(w.y), s2 = split2(w.z), s3 = split2(w.w);
        hv[0] = s0.hi; lv[0] = s0.lo;
        hv[1] = s1.hi; lv[1] = s1.lo;
        hv[2] = s2.hi; lv[2] = s2.lo;
        hv[3] = s3.hi; lv[3] = s3.lo;
        int dst = (f * 64 + L) * 8 + q * 4;
        *(short4v*)&Wfh[dst] = hv;
        *(short4v*)&Wfl[dst] = lv;
    }
    __syncthreads();

    const int j15  = lane & 15;
    const int hgrp = lane >> 4;
    const float bj0 = b_phi[j15], bj1 = b_phi[16 + j15], bj2 = b_phi[32 + j15];

    // ---------------- Phi via MFMA, per 16-sample group ------------------
    float ph[48];
    #pragma unroll
    for (int g = 0; g < 4; ++g) {
        const float* ap = obs + (size_t)(wavebase + g * 16 + j15) * 48 + 8 * hgrp;
        float a0[8], a1[8];
        {
            float4 u0 = *(const float4*)(ap);
            float4 u1 = *(const float4*)(ap + 4);
            a0[0]=u0.x; a0[1]=u0.y; a0[2]=u0.z; a0[3]=u0.w;
            a0[4]=u1.x; a0[5]=u1.y; a0[6]=u1.z; a0[7]=u1.w;
            if (hgrp < 2) {
                float4 u2 = *(const float4*)(ap + 32);
                float4 u3 = *(const float4*)(ap + 36);
                a1[0]=u2.x; a1[1]=u2.y; a1[2]=u2.z; a1[3]=u2.w;
                a1[4]=u3.x; a1[5]=u3.y; a1[6]=u3.z; a1[7]=u3.w;
            } else {
                #pragma unroll
                for (int i = 0; i < 8; ++i) a1[i] = 0.0f;
            }
        }
        short8 a0h, a0l, a1h, a1l;
        split8(a0, a0h, a0l);
        split8(a1, a1h, a1l);

        float4v c0 = {0.f,0.f,0.f,0.f}, c1 = c0, c2 = c0;
        short8 wh, wl;
        wh = *(const short8*)&Wfh[(0*64 + lane)*8];
        wl = *(const short8*)&Wfl[(0*64 + lane)*8];
        MF(c0, a0h, wh); MF(c0, a0h, wl); MF(c0, a0l, wh);
        wh = *(const short8*)&Wfh[(2*64 + lane)*8];
        wl = *(const short8*)&Wfl[(2*64 + lane)*8];
        MF(c1, a0h, wh); MF(c1, a0h, wl); MF(c1, a0l, wh);
        wh = *(const short8*)&Wfh[(4*64 + lane)*8];
        wl = *(const short8*)&Wfl[(4*64 + lane)*8];
        MF(c2, a0h, wh); MF(c2, a0h, wl); MF(c2, a0l, wh);
        wh = *(const short8*)&Wfh[(1*64 + lane)*8];
        wl = *(const short8*)&Wfl[(1*64 + lane)*8];
        MF(c0, a1h, wh); MF(c0, a1h, wl); MF(c0, a1l, wh);
        wh = *(const short8*)&Wfh[(3*64 + lane)*8];
        wl = *(const short8*)&Wfl[(3*64 + lane)*8];
        MF(c1, a1h, wh); MF(c1, a1h, wl); MF(c1, a1l, wh);
        wh = *(const short8*)&Wfh[(5*64 + lane)*8];
        wl = *(const short8*)&Wfl[(5*64 + lane)*8];
        MF(c2, a1h, wh); MF(c2, a1h, wl); MF(c2, a1l, wh);

        #pragma unroll
        for (int r = 0; r < 4; ++r) {
            int rowbase = (4 * hgrp + r) * 52;
            buf[wave][rowbase +  0 + j15] = c0[r] + bj0;
            buf[wave][rowbase + 16 + j15] = c1[r] + bj1;
            buf[wave][rowbase + 32 + j15] = c2[r] + bj2;
        }
        if (hgrp == g) {
            #pragma unroll
            for (int qq = 0; qq < 12; ++qq)
                *(float4v*)&ph[qq * 4] = *(const float4v*)&buf[wave][j15 * 52 + qq * 4];
        }
    }

    // ---------------- VI setup: crd[d][cell] = rin_p[nbr] - rout[cell] ---
    float p_[16], crd[4][16];
    {
        constexpr int DHs[4] = {0, 0, -1, 1};
        constexpr int DWs[4] = {-1, 1, 0, 0};
        #pragma unroll
        for (int c = 0; c < 16; ++c) p_[c] = ph[3 * c + 2];
        #pragma unroll
        for (int h = 0; h < 4; ++h) {
            #pragma unroll
            for (int w = 0; w < 4; ++w) {
                const int cell = h * 4 + w;
                const float nr = -ph[3 * cell + 1];
                #pragma unroll
                for (int d = 0; d < 4; ++d) {
                    const int hh = h + DHs[d], ww = w + DWs[d];
                    if (hh >= 0 && hh < 4 && ww >= 0 && ww < 4)
                        crd[d][cell] = ph[3 * (hh * 4 + ww)] + nr;
                    else
                        crd[d][cell] = nr;
                }
            }
        }
    }

    // step 1 folded: v0=0 -> every candidate is exactly crd; include 0 (old v)
    float v[16], nv[16];
    const float zero = 0.0f;
    #pragma unroll
    for (int c = 0; c < 16; ++c)
        v[c] = max3f(max3f(crd[0][c], crd[1][c], crd[2][c]), crd[3][c], zero);

    // steps 2..20: OOB candidates dropped (exact: -rout <= v1 <= v_t)
#define CAND_L fmaf(p_[c], SRC[c - 1], crd[0][c])
#define CAND_R fmaf(p_[c], SRC[c + 1], crd[1][c])
#define CAND_U fmaf(p_[c], SRC[c - 4], crd[2][c])
#define CAND_D fmaf(p_[c], SRC[c + 4], crd[3][c])
#define VI_STEP(S_, D_)                                                       \
    {                                                                         \
        const float* SRC = S_;                                                \
        float* DST = D_;                                                      \
        _Pragma("unroll")                                                     \
        for (int h = 0; h < 4; ++h) {                                         \
            _Pragma("unroll")                                                 \
            for (int w = 0; w < 4; ++w) {                                     \
                const int c = h * 4 + w;                                      \
                const bool Ld = (w > 0), Rd = (w < 3), Ud = (h > 0), Dd = (h < 3); \
                if (!Ld) {                                                    \
                    if (!Ud)      DST[c] = max3f(CAND_R, CAND_D, SRC[c]);     \
                    else if (!Dd) DST[c] = max3f(CAND_R, CAND_U, SRC[c]);     \
                    else          DST[c] = fmaxf(max3f(CAND_R, CAND_U, CAND_D), SRC[c]); \
                } else if (!Rd) {                                             \
                    if (!Ud)      DST[c] = max3f(CAND_L, CAND_D, SRC[c]);     \
                    else if (!Dd) DST[c] = max3f(CAND_L, CAND_U, SRC[c]);     \
                    else          DST[c] = fmaxf(max3f(CAND_L, CAND_U, CAND_D), SRC[c]); \
                } else if (!Ud) {                                             \
                    DST[c] = fmaxf(max3f(CAND_L, CAND_R, CAND_D), SRC[c]);    \
                } else if (!Dd) {                                             \
                    DST[c] = fmaxf(max3f(CAND_L, CAND_R, CAND_U), SRC[c]);    \
                } else {                                                      \
                    DST[c] = max3f(max3f(CAND_L, CAND_R, CAND_U), CAND_D, SRC[c]); \
                }                                                             \
            }                                                                 \
        }                                                                     \
    }

    #pragma unroll 1
    for (int it = 0; it < 9; ++it) {   // steps 2..19
        VI_STEP(v, nv)
        VI_STEP(nv, v)
    }
    VI_STEP(v, nv)                     // step 20; final state in nv
#undef VI_STEP
#undef CAND_L
#undef CAND_R
#undef CAND_U
#undef CAND_D
    // final V (post-transpose): V[h][w] = nv[w*4 + h]

    // ---------------- tail: own-row loads AFTER VI (frees 12 regs in VI) -
    const float* orow = obs + (size_t)smp * 48;
    float4 q0   = *(const float4*)(orow + 0);    // o0..o3
    float2 o45  = *(const float2*)(orow + 4);    // o4,o5
    float4 q3   = *(const float4*)(orow + 12);   // o12..o15
    float2 o167 = *(const float2*)(orow + 16);   // o16,o17

    float lg[4];
    if (q0.y != 0.0f) {   // o[1]!=0 <=> first-nonzero cell is 0 (fast path)
        #pragma unroll
        for (int a = 0; a < 4; ++a) {
            const float* Wl = W_logit + a * 36;
            float acc = b_logit[a];
            acc = fmaf(q0.x,   Wl[12], acc);
            acc = fmaf(q0.y,   Wl[13], acc);
            acc = fmaf(q0.z,   Wl[14], acc);
            acc = fmaf(q0.w,   Wl[15], acc);
            acc = fmaf(o45.x,  Wl[16], acc);
            acc = fmaf(o45.y,  Wl[17], acc);
            acc = fmaf(q3.x,   Wl[21], acc);
            acc = fmaf(q3.y,   Wl[22], acc);
            acc = fmaf(q3.z,   Wl[23], acc);
            acc = fmaf(q3.w,   Wl[24], acc);
            acc = fmaf(o167.x, Wl[25], acc);
            acc = fmaf(o167.y, Wl[26], acc);
            acc = fmaf(nv[0],  Wl[31], acc);   // V[0][0]
            acc = fmaf(nv[4],  Wl[32], acc);   // V[0][1]
            acc = fmaf(nv[1],  Wl[34], acc);   // V[1][0]
            acc = fmaf(nv[5],  Wl[35], acc);   // V[1][1]
            lg[a] = acc;
        }
    } else {
        // generic path (never taken for N(0,1) data; kept for correctness)
        int idx = 16;
        #pragma unroll
        for (int cell = 15; cell >= 0; --cell)
            if (orow[3 * cell + 1] != 0.0f) idx = cell;
        const int ai = (idx == 16) ? 1 : (idx >> 2);
        const int aj = (idx == 16) ? 1 : (idx & 3);
        #pragma unroll
        for (int h = 0; h < 4; ++h)
            #pragma unroll
            for (int w = 0; w < 4; ++w)
                buf[wave][lane * 13 + h * 4 + w] = nv[w * 4 + h];   // V[h][w]
        float li[36];
        #pragma unroll
        for (int a = 0; a < 3; ++a) {
            #pragma unroll
            for (int b = 0; b < 3; ++b) {
                const int hh = ai + a - 1, ww = aj + b - 1;
                const bool inb = (hh >= 0) && (hh < 4) && (ww >= 0) && (ww < 4);
                const int cl = inb ? (hh * 4 + ww) : 0;
                #pragma unroll
                for (int c = 0; c < 3; ++c)
                    li[a * 9 + b * 3 + c] = inb ? orow[cl * 3 + c] : 0.0f;
                li[27 + a * 3 + b] = inb ? buf[wave][lane * 13 + cl] : 0.0f;
            }
        }
        #pragma unroll
        for (int a = 0; a < 4; ++a) {
            float acc = b_logit[a];
            #pragma unroll
            for (int m = 0; m < 36; ++m)
                acc = fmaf(li[m], W_logit[a * 36 + m], acc);
            lg[a] = acc;
        }
    }

    *(float4*)(out + (size_t)smp * 4) = make_float4(lg[0], lg[1], lg[2], lg[3]);
}

extern "C" void kernel_launch(void* const* d_in, const int* in_sizes, int n_in,
                              void* d_out, int out_size, void* d_ws, size_t ws_size,
                              hipStream_t stream) {
    const float* obs     = (const float*)d_in[0];
    const float* W_phi   = (const float*)d_in[1];
    const float* b_phi   = (const float*)d_in[2];
    const float* W_logit = (const float*)d_in[3];
    const float* b_logit = (const float*)d_in[4];
    float* out = (float*)d_out;
    (void)d_ws; (void)ws_size; (void)n_in;

    const int B = in_sizes[0] / 48;
    const int grid = B / 1024;
    vpn_kernel<<<grid, 1024, 0, stream>>>(obs, W_phi, b_phi, W_logit, b_logit, out, B);
}

// Round 17
// 22.582 us; speedup vs baseline: 1.1033x; 1.1033x over previous
//
#include <hip/hip_runtime.h>

typedef __attribute__((ext_vector_type(8))) short short8;
typedef __attribute__((ext_vector_type(4))) short short4v;
typedef __attribute__((ext_vector_type(4))) float float4v;

static __device__ __forceinline__ short f2bf(float x) {
    unsigned u = __float_as_uint(x);
    unsigned r = (u + 0x7FFFu + ((u >> 16) & 1u)) >> 16;   // RNE
    return (short)r;
}
static __device__ __forceinline__ float bf2f(short h) {
    return __uint_as_float(((unsigned)(unsigned short)h) << 16);
}
struct BfPair { short hi, lo; };
static __device__ __forceinline__ BfPair split2(float x) {   // W staging only
    BfPair r;
    r.hi = f2bf(x);
    r.lo = f2bf(x - bf2f(r.hi));
    return r;
}

static __device__ __forceinline__ unsigned cvt_pk_bf16(float a, float b) {
    unsigned r;
    asm("v_cvt_pk_bf16_f32 %0, %1, %2" : "=v"(r) : "v"(a), "v"(b));
    return r;   // low16 = bf16(a), high16 = bf16(b)
}

// R4-R7-proven split: hi = truncation (bit ops, residual exact), lo = RNE of
// residual via cvt_pk. (cvt_pk-based HI plane fails correctness — R9/R10.)
static __device__ __forceinline__ void split8(const float x[8], short8& hi, short8& lo) {
    union U { short8 s; unsigned u[4]; } H, L;
    #pragma unroll
    for (int q = 0; q < 4; ++q) {
        unsigned ue = __float_as_uint(x[2*q]);
        unsigned uo = __float_as_uint(x[2*q+1]);
        H.u[q] = (ue >> 16) | (uo & 0xFFFF0000u);
        float re = x[2*q]   - __uint_as_float(ue & 0xFFFF0000u);
        float ro = x[2*q+1] - __uint_as_float(uo & 0xFFFF0000u);
        L.u[q] = cvt_pk_bf16(re, ro);
    }
    hi = H.s; lo = L.s;
}

// Native 3-way max: LLVM AMDGPU fuses maxnum(maxnum(a,b),c) -> v_max3_f32
// WITHOUT inline-asm operand-marshaling movs (R17 experiment: the 532 asm
// max3 sites were the suspected source of the ~2x executed-instr inflation).
static __device__ __forceinline__ float m3(float a, float b, float c) {
    return fmaxf(fmaxf(a, b), c);
}

#define MF(c, a, b) c = __builtin_amdgcn_mfma_f32_16x16x32_bf16(a, b, c, 0, 0, 0)

// Block = 1024 threads (16 waves), one sample per thread, (1024,2) -> 128-reg
// cap, 4 waves/SIMD.
__global__ __launch_bounds__(1024, 2) void vpn_kernel(
    const float* __restrict__ obs,
    const float* __restrict__ W_phi,
    const float* __restrict__ b_phi,
    const float* __restrict__ W_logit,
    const float* __restrict__ b_logit,
    float* __restrict__ out, int B)
{
    __shared__ __align__(16) unsigned short Wfh[6 * 64 * 8];   //  6144 B
    __shared__ __align__(16) unsigned short Wfl[6 * 64 * 8];   //  6144 B
    __shared__ __align__(16) float buf[16][840];               // 53760 B

    const int t    = threadIdx.x;
    const int lane = t & 63;
    const int wave = t >> 6;
    const int smp  = blockIdx.x * 1024 + t;
    const int wavebase = blockIdx.x * 1024 + wave * 64;

    // ---------------- stage W fragments (once per block) ----------------
    if (t < 768) {
        int H = t;                            // 0..767 half-fragments
        int f = H >> 7, rem = H & 127;
        int L = rem >> 1, q = rem & 1;
        int jt = f >> 1, kc = f & 1;
        int j = jt * 16 + (L & 15), h = L >> 4;
        int k = kc * 32 + h * 8 + q * 4;
        float4 w = make_float4(0.f, 0.f, 0.f, 0.f);
        if (k < 48) w = *(const float4*)(W_phi + j * 48 + k);
        short4v hv, lv;
        BfPair s0 = split2(w.x), s1 = split2(w.y), s2 = split2(w.z), s3 = split2(w.w);
        hv[0] = s0.hi; lv[0] = s0.lo;
        hv[1] = s1.hi; lv[1] = s1.lo;
        hv[2] = s2.hi; lv[2] = s2.lo;
        hv[3] = s3.hi; lv[3] = s3.lo;
        int dst = (f * 64 + L) * 8 + q * 4;
        *(short4v*)&Wfh[dst] = hv;
        *(short4v*)&Wfl[dst] = lv;
    }
    __syncthreads();

    const int j15  = lane & 15;
    const int hgrp = lane >> 4;
    const float bj0 = b_phi[j15], bj1 = b_phi[16 + j15], bj2 = b_phi[32 + j15];

    // ---------------- Phi via MFMA, per 16-sample group ------------------
    float ph[48];
    #pragma unroll
    for (int g = 0; g < 4; ++g) {
        const float* ap = obs + (size_t)(wavebase + g * 16 + j15) * 48 + 8 * hgrp;
        float a0[8], a1[8];
        {
            float4 u0 = *(const float4*)(ap);
            float4 u1 = *(const float4*)(ap + 4);
            a0[0]=u0.x; a0[1]=u0.y; a0[2]=u0.z; a0[3]=u0.w;
            a0[4]=u1.x; a0[5]=u1.y; a0[6]=u1.z; a0[7]=u1.w;
            if (hgrp < 2) {
                float4 u2 = *(const float4*)(ap + 32);
                float4 u3 = *(const float4*)(ap + 36);
                a1[0]=u2.x; a1[1]=u2.y; a1[2]=u2.z; a1[3]=u2.w;
                a1[4]=u3.x; a1[5]=u3.y; a1[6]=u3.z; a1[7]=u3.w;
            } else {
                #pragma unroll
                for (int i = 0; i < 8; ++i) a1[i] = 0.0f;
            }
        }
        short8 a0h, a0l, a1h, a1l;
        split8(a0, a0h, a0l);
        split8(a1, a1h, a1l);

        float4v c0 = {0.f,0.f,0.f,0.f}, c1 = c0, c2 = c0;
        short8 wh, wl;
        wh = *(const short8*)&Wfh[(0*64 + lane)*8];
        wl = *(const short8*)&Wfl[(0*64 + lane)*8];
        MF(c0, a0h, wh); MF(c0, a0h, wl); MF(c0, a0l, wh);
        wh = *(const short8*)&Wfh[(2*64 + lane)*8];
        wl = *(const short8*)&Wfl[(2*64 + lane)*8];
        MF(c1, a0h, wh); MF(c1, a0h, wl); MF(c1, a0l, wh);
        wh = *(const short8*)&Wfh[(4*64 + lane)*8];
        wl = *(const short8*)&Wfl[(4*64 + lane)*8];
        MF(c2, a0h, wh); MF(c2, a0h, wl); MF(c2, a0l, wh);
        wh = *(const short8*)&Wfh[(1*64 + lane)*8];
        wl = *(const short8*)&Wfl[(1*64 + lane)*8];
        MF(c0, a1h, wh); MF(c0, a1h, wl); MF(c0, a1l, wh);
        wh = *(const short8*)&Wfh[(3*64 + lane)*8];
        wl = *(const short8*)&Wfl[(3*64 + lane)*8];
        MF(c1, a1h, wh); MF(c1, a1h, wl); MF(c1, a1l, wh);
        wh = *(const short8*)&Wfh[(5*64 + lane)*8];
        wl = *(const short8*)&Wfl[(5*64 + lane)*8];
        MF(c2, a1h, wh); MF(c2, a1h, wl); MF(c2, a1l, wh);

        #pragma unroll
        for (int r = 0; r < 4; ++r) {
            int rowbase = (4 * hgrp + r) * 52;
            buf[wave][rowbase +  0 + j15] = c0[r] + bj0;
            buf[wave][rowbase + 16 + j15] = c1[r] + bj1;
            buf[wave][rowbase + 32 + j15] = c2[r] + bj2;
        }
        if (hgrp == g) {
            #pragma unroll
            for (int qq = 0; qq < 12; ++qq)
                *(float4v*)&ph[qq * 4] = *(const float4v*)&buf[wave][j15 * 52 + qq * 4];
        }
    }

    // -------- tail prefetch (fast-path values only; hidden under VI) -----
    const float* orow = obs + (size_t)smp * 48;
    float4 q0   = *(const float4*)(orow + 0);    // o0..o3
    float2 o45  = *(const float2*)(orow + 4);    // o4,o5
    float4 q3   = *(const float4*)(orow + 12);   // o12..o15
    float2 o167 = *(const float2*)(orow + 16);   // o16,o17

    // ---------------- VI setup: crd[d][cell] = rin_p[nbr] - rout[cell] ---
    float p_[16], crd[4][16];
    {
        constexpr int DHs[4] = {0, 0, -1, 1};
        constexpr int DWs[4] = {-1, 1, 0, 0};
        #pragma unroll
        for (int c = 0; c < 16; ++c) p_[c] = ph[3 * c + 2];
        #pragma unroll
        for (int h = 0; h < 4; ++h) {
            #pragma unroll
            for (int w = 0; w < 4; ++w) {
                const int cell = h * 4 + w;
                const float nr = -ph[3 * cell + 1];
                #pragma unroll
                for (int d = 0; d < 4; ++d) {
                    const int hh = h + DHs[d], ww = w + DWs[d];
                    if (hh >= 0 && hh < 4 && ww >= 0 && ww < 4)
                        crd[d][cell] = ph[3 * (hh * 4 + ww)] + nr;
                    else
                        crd[d][cell] = nr;
                }
            }
        }
    }

    // step 1 folded: v0=0 -> every candidate is exactly crd; include 0 (old v)
    float v[16], nv[16];
    #pragma unroll
    for (int c = 0; c < 16; ++c)
        v[c] = m3(m3(crd[0][c], crd[1][c], crd[2][c]), crd[3][c], 0.0f);

    // steps 2..20: OOB candidates dropped (exact: -rout <= v1 <= v_t)
#define CAND_L fmaf(p_[c], SRC[c - 1], crd[0][c])
#define CAND_R fmaf(p_[c], SRC[c + 1], crd[1][c])
#define CAND_U fmaf(p_[c], SRC[c - 4], crd[2][c])
#define CAND_D fmaf(p_[c], SRC[c + 4], crd[3][c])
#define VI_STEP(S_, D_)                                                       \
    {                                                                         \
        const float* SRC = S_;                                                \
        float* DST = D_;                                                      \
        _Pragma("unroll")                                                     \
        for (int h = 0; h < 4; ++h) {                                         \
            _Pragma("unroll")                                                 \
            for (int w = 0; w < 4; ++w) {                                     \
                const int c = h * 4 + w;                                      \
                const bool Ld = (w > 0), Rd = (w < 3), Ud = (h > 0), Dd = (h < 3); \
                if (!Ld) {                                                    \
                    if (!Ud)      DST[c] = m3(CAND_R, CAND_D, SRC[c]);        \
                    else if (!Dd) DST[c] = m3(CAND_R, CAND_U, SRC[c]);        \
                    else          DST[c] = fmaxf(m3(CAND_R, CAND_U, CAND_D), SRC[c]); \
                } else if (!Rd) {                                             \
                    if (!Ud)      DST[c] = m3(CAND_L, CAND_D, SRC[c]);        \
                    else if (!Dd) DST[c] = m3(CAND_L, CAND_U, SRC[c]);        \
                    else          DST[c] = fmaxf(m3(CAND_L, CAND_U, CAND_D), SRC[c]); \
                } else if (!Ud) {                                             \
                    DST[c] = fmaxf(m3(CAND_L, CAND_R, CAND_D), SRC[c]);       \
                } else if (!Dd) {                                             \
                    DST[c] = fmaxf(m3(CAND_L, CAND_R, CAND_U), SRC[c]);       \
                } else {                                                      \
                    DST[c] = m3(m3(CAND_L, CAND_R, CAND_U), CAND_D, SRC[c]);  \
                }                                                             \
            }                                                                 \
        }                                                                     \
    }

    #pragma unroll 1
    for (int it = 0; it < 9; ++it) {   // steps 2..19
        VI_STEP(v, nv)
        VI_STEP(nv, v)
    }
    VI_STEP(v, nv)                     // step 20; final state in nv
#undef VI_STEP
#undef CAND_L
#undef CAND_R
#undef CAND_U
#undef CAND_D
    // final V (post-transpose): V[h][w] = nv[w*4 + h]

    // ---------------- extraction + logit --------------------------------
    float lg[4];
    if (q0.y != 0.0f) {   // o[1]!=0 <=> first-nonzero cell is 0 (fast path)
        #pragma unroll
        for (int a = 0; a < 4; ++a) {
            const float* Wl = W_logit + a * 36;
            float acc = b_logit[a];
            acc = fmaf(q0.x,   Wl[12], acc);
            acc = fmaf(q0.y,   Wl[13], acc);
            acc = fmaf(q0.z,   Wl[14], acc);
            acc = fmaf(q0.w,   Wl[15], acc);
            acc = fmaf(o45.x,  Wl[16], acc);
            acc = fmaf(o45.y,  Wl[17], acc);
            acc = fmaf(q3.x,   Wl[21], acc);
            acc = fmaf(q3.y,   Wl[22], acc);
            acc = fmaf(q3.z,   Wl[23], acc);
            acc = fmaf(q3.w,   Wl[24], acc);
            acc = fmaf(o167.x, Wl[25], acc);
            acc = fmaf(o167.y, Wl[26], acc);
            acc = fmaf(nv[0],  Wl[31], acc);   // V[0][0]
            acc = fmaf(nv[4],  Wl[32], acc);   // V[0][1]
            acc = fmaf(nv[1],  Wl[34], acc);   // V[1][0]
            acc = fmaf(nv[5],  Wl[35], acc);   // V[1][1]
            lg[a] = acc;
        }
    } else {
        // generic path (never taken for N(0,1) data; kept for correctness)
        int idx = 16;
        #pragma unroll
        for (int cell = 15; cell >= 0; --cell)
            if (orow[3 * cell + 1] != 0.0f) idx = cell;
        const int ai = (idx == 16) ? 1 : (idx >> 2);
        const int aj = (idx == 16) ? 1 : (idx & 3);
        #pragma unroll
        for (int h = 0; h < 4; ++h)
            #pragma unroll
            for (int w = 0; w < 4; ++w)
                buf[wave][lane * 13 + h * 4 + w] = nv[w * 4 + h];   // V[h][w]
        float li[36];
        #pragma unroll
        for (int a = 0; a < 3; ++a) {
            #pragma unroll
            for (int b = 0; b < 3; ++b) {
                const int hh = ai + a - 1, ww = aj + b - 1;
                const bool inb = (hh >= 0) && (hh < 4) && (ww >= 0) && (ww < 4);
                const int cl = inb ? (hh * 4 + ww) : 0;
                #pragma unroll
                for (int c = 0; c < 3; ++c)
                    li[a * 9 + b * 3 + c] = inb ? orow[cl * 3 + c] : 0.0f;
                li[27 + a * 3 + b] = inb ? buf[wave][lane * 13 + cl] : 0.0f;
            }
        }
        #pragma unroll
        for (int a = 0; a < 4; ++a) {
            float acc = b_logit[a];
            #pragma unroll
            for (int m = 0; m < 36; ++m)
                acc = fmaf(li[m], W_logit[a * 36 + m], acc);
            lg[a] = acc;
        }
    }

    *(float4*)(out + (size_t)smp * 4) = make_float4(lg[0], lg[1], lg[2], lg[3]);
}

extern "C" void kernel_launch(void* const* d_in, const int* in_sizes, int n_in,
                              void* d_out, int out_size, void* d_ws, size_t ws_size,
                              hipStream_t stream) {
    const float* obs     = (const float*)d_in[0];
    const float* W_phi   = (const float*)d_in[1];
    const float* b_phi   = (const float*)d_in[2];
    const float* W_logit = (const float*)d_in[3];
    const float* b_logit = (const float*)d_in[4];
    float* out = (float*)d_out;
    (void)d_ws; (void)ws_size; (void)n_in;

    const int B = in_sizes[0] / 48;
    const int grid = B / 1024;
    vpn_kernel<<<grid, 1024, 0, stream>>>(obs, W_phi, b_phi, W_logit, b_logit, out, B);
}

// Round 19
// 22.434 us; speedup vs baseline: 1.1106x; 1.0066x over previous
//
#include <hip/hip_runtime.h>

typedef __attribute__((ext_vector_type(8))) short short8;
typedef __attribute__((ext_vector_type(4))) short short4v;
typedef __attribute__((ext_vector_type(4))) float float4v;

static __device__ __forceinline__ short f2bf(float x) {
    unsigned u = __float_as_uint(x);
    unsigned r = (u + 0x7FFFu + ((u >> 16) & 1u)) >> 16;   // RNE
    return (short)r;
}
static __device__ __forceinline__ float bf2f(short h) {
    return __uint_as_float(((unsigned)(unsigned short)h) << 16);
}
struct BfPair { short hi, lo; };
static __device__ __forceinline__ BfPair split2(float x) {   // W staging only
    BfPair r;
    r.hi = f2bf(x);
    r.lo = f2bf(x - bf2f(r.hi));
    return r;
}

static __device__ __forceinline__ unsigned cvt_pk_bf16(float a, float b) {
    unsigned r;
    asm("v_cvt_pk_bf16_f32 %0, %1, %2" : "=v"(r) : "v"(a), "v"(b));
    return r;   // low16 = bf16(a), high16 = bf16(b)
}

// R4-R7-proven split: hi = truncation (bit ops, residual exact), lo = RNE of
// residual via cvt_pk. (cvt_pk-based HI plane fails correctness — R9/R10.)
static __device__ __forceinline__ void split8(const float x[8], short8& hi, short8& lo) {
    union U { short8 s; unsigned u[4]; } H, L;
    #pragma unroll
    for (int q = 0; q < 4; ++q) {
        unsigned ue = __float_as_uint(x[2*q]);
        unsigned uo = __float_as_uint(x[2*q+1]);
        H.u[q] = (ue >> 16) | (uo & 0xFFFF0000u);
        float re = x[2*q]   - __uint_as_float(ue & 0xFFFF0000u);
        float ro = x[2*q+1] - __uint_as_float(uo & 0xFFFF0000u);
        L.u[q] = cvt_pk_bf16(re, ro);
    }
    hi = H.s; lo = L.s;
}

// Native 3-way max: LLVM AMDGPU fuses maxnum(maxnum(a,b),c) -> v_max3_f32
// WITHOUT inline-asm operand-marshaling movs (R17 win: -1.4us vs asm max3).
static __device__ __forceinline__ float m3(float a, float b, float c) {
    return fmaxf(fmaxf(a, b), c);
}

#define MF(c, a, b) c = __builtin_amdgcn_mfma_f32_16x16x32_bf16(a, b, c, 0, 0, 0)

// Block = 1024 threads (16 waves), one sample per thread, (1024,2) -> 128-reg
// cap, 4 waves/SIMD. Final kernel = R17 (best verified: 22.58us, 2.3x over
// the 52us scalar baseline). R18's block-512 variant failed correctness for
// an unlocalized reason and is abandoned.
__global__ __launch_bounds__(1024, 2) void vpn_kernel(
    const float* __restrict__ obs,
    const float* __restrict__ W_phi,
    const float* __restrict__ b_phi,
    const float* __restrict__ W_logit,
    const float* __restrict__ b_logit,
    float* __restrict__ out, int B)
{
    __shared__ __align__(16) unsigned short Wfh[6 * 64 * 8];   //  6144 B
    __shared__ __align__(16) unsigned short Wfl[6 * 64 * 8];   //  6144 B
    __shared__ __align__(16) float buf[16][840];               // 53760 B

    const int t    = threadIdx.x;
    const int lane = t & 63;
    const int wave = t >> 6;
    const int smp  = blockIdx.x * 1024 + t;
    const int wavebase = blockIdx.x * 1024 + wave * 64;

    // ---------------- stage W fragments (once per block) ----------------
    if (t < 768) {
        int H = t;                            // 0..767 half-fragments
        int f = H >> 7, rem = H & 127;
        int L = rem >> 1, q = rem & 1;
        int jt = f >> 1, kc = f & 1;
        int j = jt * 16 + (L & 15), h = L >> 4;
        int k = kc * 32 + h * 8 + q * 4;
        float4 w = make_float4(0.f, 0.f, 0.f, 0.f);
        if (k < 48) w = *(const float4*)(W_phi + j * 48 + k);
        short4v hv, lv;
        BfPair s0 = split2(w.x), s1 = split2(w.y), s2 = split2(w.z), s3 = split2(w.w);
        hv[0] = s0.hi; lv[0] = s0.lo;
        hv[1] = s1.hi; lv[1] = s1.lo;
        hv[2] = s2.hi; lv[2] = s2.lo;
        hv[3] = s3.hi; lv[3] = s3.lo;
        int dst = (f * 64 + L) * 8 + q * 4;
        *(short4v*)&Wfh[dst] = hv;
        *(short4v*)&Wfl[dst] = lv;
    }
    __syncthreads();

    const int j15  = lane & 15;
    const int hgrp = lane >> 4;
    const float bj0 = b_phi[j15], bj1 = b_phi[16 + j15], bj2 = b_phi[32 + j15];

    // ---------------- Phi via MFMA, per 16-sample group ------------------
    float ph[48];
    #pragma unroll
    for (int g = 0; g < 4; ++g) {
        const float* ap = obs + (size_t)(wavebase + g * 16 + j15) * 48 + 8 * hgrp;
        float a0[8], a1[8];
        {
            float4 u0 = *(const float4*)(ap);
            float4 u1 = *(const float4*)(ap + 4);
            a0[0]=u0.x; a0[1]=u0.y; a0[2]=u0.z; a0[3]=u0.w;
            a0[4]=u1.x; a0[5]=u1.y; a0[6]=u1.z; a0[7]=u1.w;
            if (hgrp < 2) {
                float4 u2 = *(const float4*)(ap + 32);
                float4 u3 = *(const float4*)(ap + 36);
                a1[0]=u2.x; a1[1]=u2.y; a1[2]=u2.z; a1[3]=u2.w;
                a1[4]=u3.x; a1[5]=u3.y; a1[6]=u3.z; a1[7]=u3.w;
            } else {
                #pragma unroll
                for (int i = 0; i < 8; ++i) a1[i] = 0.0f;
            }
        }
        short8 a0h, a0l, a1h, a1l;
        split8(a0, a0h, a0l);
        split8(a1, a1h, a1l);

        float4v c0 = {0.f,0.f,0.f,0.f}, c1 = c0, c2 = c0;
        short8 wh, wl;
        wh = *(const short8*)&Wfh[(0*64 + lane)*8];
        wl = *(const short8*)&Wfl[(0*64 + lane)*8];
        MF(c0, a0h, wh); MF(c0, a0h, wl); MF(c0, a0l, wh);
        wh = *(const short8*)&Wfh[(2*64 + lane)*8];
        wl = *(const short8*)&Wfl[(2*64 + lane)*8];
        MF(c1, a0h, wh); MF(c1, a0h, wl); MF(c1, a0l, wh);
        wh = *(const short8*)&Wfh[(4*64 + lane)*8];
        wl = *(const short8*)&Wfl[(4*64 + lane)*8];
        MF(c2, a0h, wh); MF(c2, a0h, wl); MF(c2, a0l, wh);
        wh = *(const short8*)&Wfh[(1*64 + lane)*8];
        wl = *(const short8*)&Wfl[(1*64 + lane)*8];
        MF(c0, a1h, wh); MF(c0, a1h, wl); MF(c0, a1l, wh);
        wh = *(const short8*)&Wfh[(3*64 + lane)*8];
        wl = *(const short8*)&Wfl[(3*64 + lane)*8];
        MF(c1, a1h, wh); MF(c1, a1h, wl); MF(c1, a1l, wh);
        wh = *(const short8*)&Wfh[(5*64 + lane)*8];
        wl = *(const short8*)&Wfl[(5*64 + lane)*8];
        MF(c2, a1h, wh); MF(c2, a1h, wl); MF(c2, a1l, wh);

        #pragma unroll
        for (int r = 0; r < 4; ++r) {
            int rowbase = (4 * hgrp + r) * 52;
            buf[wave][rowbase +  0 + j15] = c0[r] + bj0;
            buf[wave][rowbase + 16 + j15] = c1[r] + bj1;
            buf[wave][rowbase + 32 + j15] = c2[r] + bj2;
        }
        if (hgrp == g) {
            #pragma unroll
            for (int qq = 0; qq < 12; ++qq)
                *(float4v*)&ph[qq * 4] = *(const float4v*)&buf[wave][j15 * 52 + qq * 4];
        }
    }

    // -------- tail prefetch (fast-path values only; hidden under VI) -----
    const float* orow = obs + (size_t)smp * 48;
    float4 q0   = *(const float4*)(orow + 0);    // o0..o3
    float2 o45  = *(const float2*)(orow + 4);    // o4,o5
    float4 q3   = *(const float4*)(orow + 12);   // o12..o15
    float2 o167 = *(const float2*)(orow + 16);   // o16,o17

    // ---------------- VI setup: crd[d][cell] = rin_p[nbr] - rout[cell] ---
    float p_[16], crd[4][16];
    {
        constexpr int DHs[4] = {0, 0, -1, 1};
        constexpr int DWs[4] = {-1, 1, 0, 0};
        #pragma unroll
        for (int c = 0; c < 16; ++c) p_[c] = ph[3 * c + 2];
        #pragma unroll
        for (int h = 0; h < 4; ++h) {
            #pragma unroll
            for (int w = 0; w < 4; ++w) {
                const int cell = h * 4 + w;
                const float nr = -ph[3 * cell + 1];
                #pragma unroll
                for (int d = 0; d < 4; ++d) {
                    const int hh = h + DHs[d], ww = w + DWs[d];
                    if (hh >= 0 && hh < 4 && ww >= 0 && ww < 4)
                        crd[d][cell] = ph[3 * (hh * 4 + ww)] + nr;
                    else
                        crd[d][cell] = nr;
                }
            }
        }
    }

    // step 1 folded: v0=0 -> every candidate is exactly crd; include 0 (old v)
    float v[16], nv[16];
    #pragma unroll
    for (int c = 0; c < 16; ++c)
        v[c] = m3(m3(crd[0][c], crd[1][c], crd[2][c]), crd[3][c], 0.0f);

    // steps 2..20: OOB candidates dropped (exact: -rout <= v1 <= v_t)
#define CAND_L fmaf(p_[c], SRC[c - 1], crd[0][c])
#define CAND_R fmaf(p_[c], SRC[c + 1], crd[1][c])
#define CAND_U fmaf(p_[c], SRC[c - 4], crd[2][c])
#define CAND_D fmaf(p_[c], SRC[c + 4], crd[3][c])
#define VI_STEP(S_, D_)                                                       \
    {                                                                         \
        const float* SRC = S_;                                                \
        float* DST = D_;                                                      \
        _Pragma("unroll")                                                     \
        for (int h = 0; h < 4; ++h) {                                         \
            _Pragma("unroll")                                                 \
            for (int w = 0; w < 4; ++w) {                                     \
                const int c = h * 4 + w;                                      \
                const bool Ld = (w > 0), Rd = (w < 3), Ud = (h > 0), Dd = (h < 3); \
                if (!Ld) {                                                    \
                    if (!Ud)      DST[c] = m3(CAND_R, CAND_D, SRC[c]);        \
                    else if (!Dd) DST[c] = m3(CAND_R, CAND_U, SRC[c]);        \
                    else          DST[c] = fmaxf(m3(CAND_R, CAND_U, CAND_D), SRC[c]); \
                } else if (!Rd) {                                             \
                    if (!Ud)      DST[c] = m3(CAND_L, CAND_D, SRC[c]);        \
                    else if (!Dd) DST[c] = m3(CAND_L, CAND_U, SRC[c]);        \
                    else          DST[c] = fmaxf(m3(CAND_L, CAND_U, CAND_D), SRC[c]); \
                } else if (!Ud) {                                             \
                    DST[c] = fmaxf(m3(CAND_L, CAND_R, CAND_D), SRC[c]);       \
                } else if (!Dd) {                                             \
                    DST[c] = fmaxf(m3(CAND_L, CAND_R, CAND_U), SRC[c]);       \
                } else {                                                      \
                    DST[c] = m3(m3(CAND_L, CAND_R, CAND_U), CAND_D, SRC[c]);  \
                }                                                             \
            }                                                                 \
        }                                                                     \
    }

    #pragma unroll 1
    for (int it = 0; it < 9; ++it) {   // steps 2..19
        VI_STEP(v, nv)
        VI_STEP(nv, v)
    }
    VI_STEP(v, nv)                     // step 20; final state in nv
#undef VI_STEP
#undef CAND_L
#undef CAND_R
#undef CAND_U
#undef CAND_D
    // final V (post-transpose): V[h][w] = nv[w*4 + h]

    // ---------------- extraction + logit --------------------------------
    float lg[4];
    if (q0.y != 0.0f) {   // o[1]!=0 <=> first-nonzero cell is 0 (fast path)
        #pragma unroll
        for (int a = 0; a < 4; ++a) {
            const float* Wl = W_logit + a * 36;
            float acc = b_logit[a];
            acc = fmaf(q0.x,   Wl[12], acc);
            acc = fmaf(q0.y,   Wl[13], acc);
            acc = fmaf(q0.z,   Wl[14], acc);
            acc = fmaf(q0.w,   Wl[15], acc);
            acc = fmaf(o45.x,  Wl[16], acc);
            acc = fmaf(o45.y,  Wl[17], acc);
            acc = fmaf(q3.x,   Wl[21], acc);
            acc = fmaf(q3.y,   Wl[22], acc);
            acc = fmaf(q3.z,   Wl[23], acc);
            acc = fmaf(q3.w,   Wl[24], acc);
            acc = fmaf(o167.x, Wl[25], acc);
            acc = fmaf(o167.y, Wl[26], acc);
            acc = fmaf(nv[0],  Wl[31], acc);   // V[0][0]
            acc = fmaf(nv[4],  Wl[32], acc);   // V[0][1]
            acc = fmaf(nv[1],  Wl[34], acc);   // V[1][0]
            acc = fmaf(nv[5],  Wl[35], acc);   // V[1][1]
            lg[a] = acc;
        }
    } else {
        // generic path (never taken for N(0,1) data; kept for correctness)
        int idx = 16;
        #pragma unroll
        for (int cell = 15; cell >= 0; --cell)
            if (orow[3 * cell + 1] != 0.0f) idx = cell;
        const int ai = (idx == 16) ? 1 : (idx >> 2);
        const int aj = (idx == 16) ? 1 : (idx & 3);
        #pragma unroll
        for (int h = 0; h < 4; ++h)
            #pragma unroll
            for (int w = 0; w < 4; ++w)
                buf[wave][lane * 13 + h * 4 + w] = nv[w * 4 + h];   // V[h][w]
        float li[36];
        #pragma unroll
        for (int a = 0; a < 3; ++a) {
            #pragma unroll
            for (int b = 0; b < 3; ++b) {
                const int hh = ai + a - 1, ww = aj + b - 1;
                const bool inb = (hh >= 0) && (hh < 4) && (ww >= 0) && (ww < 4);
                const int cl = inb ? (hh * 4 + ww) : 0;
                #pragma unroll
                for (int c = 0; c < 3; ++c)
                    li[a * 9 + b * 3 + c] = inb ? orow[cl * 3 + c] : 0.0f;
                li[27 + a * 3 + b] = inb ? buf[wave][lane * 13 + cl] : 0.0f;
            }
        }
        #pragma unroll
        for (int a = 0; a < 4; ++a) {
            float acc = b_logit[a];
            #pragma unroll
            for (int m = 0; m < 36; ++m)
                acc = fmaf(li[m], W_logit[a * 36 + m], acc);
            lg[a] = acc;
        }
    }

    *(float4*)(out + (size_t)smp * 4) = make_float4(lg[0], lg[1], lg[2], lg[3]);
}

extern "C" void kernel_launch(void* const* d_in, const int* in_sizes, int n_in,
                              void* d_out, int out_size, void* d_ws, size_t ws_size,
                              hipStream_t stream) {
    const float* obs     = (const float*)d_in[0];
    const float* W_phi   = (const float*)d_in[1];
    const float* b_phi   = (const float*)d_in[2];
    const float* W_logit = (const float*)d_in[3];
    const float* b_logit = (const float*)d_in[4];
    float* out = (float*)d_out;
    (void)d_ws; (void)ws_size; (void)n_in;

    const int B = in_sizes[0] / 48;
    const int grid = B / 1024;
    vpn_kernel<<<grid, 1024, 0, stream>>>(obs, W_phi, b_phi, W_logit, b_logit, out, B);
}